// Round 7
// baseline (196.501 us; speedup 1.0000x reference)
//
#include <hip/hip_runtime.h>
#include <cstdint>

#define DIM 768
#define SEQ 2048
#define NB 2
#define NH 16
#define HD 48
#define NROWS (NB*SEQ)   // 4096

typedef __attribute__((ext_vector_type(8))) short bf16x8;
typedef __attribute__((ext_vector_type(4))) float f32x4;
typedef __attribute__((ext_vector_type(16))) float f32x16;
typedef unsigned int u32;

__device__ __forceinline__ short f2bf(float f) {
    union { float f; uint32_t u; } v; v.f = f;
    uint32_t u = v.u;
    uint32_t r = (u + 0x7FFFu + ((u >> 16) & 1u)) >> 16;
    return (short)r;
}

// RNE pack of two f32 -> one dword of 2 bf16 (lo = first arg)
__device__ __forceinline__ u32 cvtpk(float lo, float hi) {
    u32 r;
    asm("v_cvt_pk_bf16_f32 %0, %1, %2" : "=v"(r) : "v"(lo), "v"(hi));
    return r;
}
__device__ __forceinline__ bf16x8 pack8(float4 a, float4 b) {
    int4 w = make_int4((int)cvtpk(a.x, a.y), (int)cvtpk(a.z, a.w),
                       (int)cvtpk(b.x, b.y), (int)cvtpk(b.z, b.w));
    return __builtin_bit_cast(bf16x8, w);
}

// ---------------------------------------------------------------------------
// bf16 MFMA GEMM, fused fp32->bf16 staging. C = A * B^T, B = W fp32 [768][768].
// Tile 128(M) x 96(N), BK=64 -> QKV grid 768 blocks (3.00/CU), O-proj 256
// (1.00/CU). 4 waves as 2x2; wave = 64x48 quadrant = 4x3 frags of 16x16x32.
// LDS 64-elem (128 B) rows, XOR swizzle slot^=(row&7) at stage-source and
// frag-read (verified R5 pattern). Next K-tile prefetched to regs before the
// MFMA phase (flash2-verified pattern) so global latency hides under compute.
// A_F32: A is fp32 (x) vs bf16 (ctx). OUT_F32: C fp32 (d_out) vs bf16.
// ---------------------------------------------------------------------------
template<bool A_F32, bool OUT_F32>
__global__ __launch_bounds__(256)
void gemm96(const void* __restrict__ Av,
            const float* __restrict__ B0, const float* __restrict__ B1,
            const float* __restrict__ B2,
            void* __restrict__ C0v, void* __restrict__ C1v, void* __restrict__ C2v)
{
    const float* B = B0; void* Cv = C0v;
    if (blockIdx.z == 1) { B = B1; Cv = C1v; }
    else if (blockIdx.z == 2) { B = B2; Cv = C2v; }

    __shared__ short As[128*64];
    __shared__ short Bs[96*64];

    const int tid  = threadIdx.x;
    const int lane = tid & 63;
    const int wid  = tid >> 6;
    const int wr = wid >> 1, wc = wid & 1;
    const int m  = lane & 15, kb = lane >> 4;
    const int m0 = blockIdx.y * 128, n0 = blockIdx.x * 96;

    f32x4 acc[4][3];
#pragma unroll
    for (int i = 0; i < 4; ++i)
#pragma unroll
        for (int j = 0; j < 3; ++j) acc[i][j] = (f32x4){0.f,0.f,0.f,0.f};

    bf16x8 sa[4], sb[3];

    // stage loaders: chunk c -> row=c>>3, physical slot c&7 holds logical
    // slot (c&7)^(row&7) (i.e. source k-offset is pre-swizzled).
#define LOAD_A(k0, i) {                                                       \
        int c = tid + (i)*256; int row = c >> 3, gs = (c & 7) ^ (row & 7);    \
        if (A_F32) {                                                          \
            const float* p = (const float*)Av + (size_t)(m0+row)*DIM + (k0) + gs*8; \
            sa[i] = pack8(*(const float4*)p, *(const float4*)(p+4));          \
        } else {                                                              \
            sa[i] = *(const bf16x8*)((const short*)Av + (size_t)(m0+row)*DIM + (k0) + gs*8); \
        } }
#define LOAD_B(k0, i) {                                                       \
        int c = tid + (i)*256; int row = c >> 3, gs = (c & 7) ^ (row & 7);    \
        const float* p = B + (size_t)(n0+row)*DIM + (k0) + gs*8;              \
        sb[i] = pack8(*(const float4*)p, *(const float4*)(p+4)); }

#pragma unroll
    for (int i = 0; i < 4; ++i) LOAD_A(0, i);
#pragma unroll
    for (int i = 0; i < 3; ++i) LOAD_B(0, i);

    for (int kt = 0; kt < DIM/64; ++kt) {
        __syncthreads();                       // prior iter's frag reads done
#pragma unroll
        for (int i = 0; i < 4; ++i) {
            int c = tid + i*256;
            *(bf16x8*)&As[(c>>3)*64 + (c&7)*8] = sa[i];
        }
#pragma unroll
        for (int i = 0; i < 3; ++i) {
            int c = tid + i*256;
            *(bf16x8*)&Bs[(c>>3)*64 + (c&7)*8] = sb[i];
        }
        __syncthreads();

        if (kt < DIM/64 - 1) {                 // prefetch next K-tile (T14)
            int k0 = (kt+1)*64;
#pragma unroll
            for (int i = 0; i < 4; ++i) LOAD_A(k0, i);
#pragma unroll
            for (int i = 0; i < 3; ++i) LOAD_B(k0, i);
        }

        bf16x8 af[2][4], bfr[2][3];
#pragma unroll
        for (int t = 0; t < 2; ++t) {
            int sl = ((t*4 + kb) ^ (m & 7)) * 8;
#pragma unroll
            for (int f = 0; f < 4; ++f)
                af[t][f]  = *(const bf16x8*)&As[(wr*64 + f*16 + m)*64 + sl];
#pragma unroll
            for (int f = 0; f < 3; ++f)
                bfr[t][f] = *(const bf16x8*)&Bs[(wc*48 + f*16 + m)*64 + sl];
        }
#pragma unroll
        for (int fm = 0; fm < 4; ++fm)
#pragma unroll
            for (int fn = 0; fn < 3; ++fn) {
                acc[fm][fn] = __builtin_amdgcn_mfma_f32_16x16x32_bf16(af[0][fm], bfr[0][fn], acc[fm][fn], 0, 0, 0);
                acc[fm][fn] = __builtin_amdgcn_mfma_f32_16x16x32_bf16(af[1][fm], bfr[1][fn], acc[fm][fn], 0, 0, 0);
            }
    }
#undef LOAD_A
#undef LOAD_B

    // D layout: row = kb*4+r within 16-block, col = m (R5-verified)
#pragma unroll
    for (int fm = 0; fm < 4; ++fm)
#pragma unroll
        for (int fn = 0; fn < 3; ++fn) {
            int col = n0 + wc*48 + fn*16 + m;
#pragma unroll
            for (int r = 0; r < 4; ++r) {
                int row = m0 + wr*64 + fm*16 + kb*4 + r;
                if (OUT_F32)
                    ((float*)Cv)[(size_t)row*DIM + col] = acc[fm][fn][r];
                else
                    ((short*)Cv)[(size_t)row*DIM + col] = f2bf(acc[fm][fn][r]);
            }
        }
}

// ---------------------------------------------------------------------------
// Flash attention v2 (R6-verified structure). Only change: P packing uses
// v_cvt_pk_bf16_f32 (RNE) and l is summed from fp32 p (unbiased vs packed P).
// ---------------------------------------------------------------------------
__global__ __launch_bounds__(256)
void flash2(const short* __restrict__ Qb, const short* __restrict__ Kb,
            const short* __restrict__ Vb, short* __restrict__ Ctx)
{
    __shared__ short K_lds[64*64];
    __shared__ short Vt_lds[64*68];

    const int tid  = threadIdx.x;
    const int wid  = tid >> 6, lane = tid & 63;
    const int r    = lane & 31, hi = lane >> 5;
    const size_t base = (size_t)blockIdx.z*SEQ*DIM + (size_t)blockIdx.y*HD;
    const int q0 = blockIdx.x*128 + wid*32;
    const float C2  = 0.20823688f;   // 48^-0.5 * log2(e)
    const float THR = 11.5f;         // defer-max threshold (~8 nats)

    for (int i = tid; i < 16*68; i += 256) Vt_lds[48*68 + i] = 0;

    bf16x8 qf[3];
#pragma unroll
    for (int s = 0; s < 3; ++s)
        qf[s] = *(const bf16x8*)&Qb[base + (size_t)(q0 + r)*DIM + s*16 + hi*8];

    f32x16 z16;
#pragma unroll
    for (int i = 0; i < 16; ++i) z16[i] = 0.f;

    f32x16 acc0 = z16, acc1 = z16;
    float m_i = -1e30f, l_i = 0.f;

    const int row0 = tid >> 3,       ps0 = tid & 7;
    const int row1 = (tid+256) >> 3, ps1 = tid & 7;
    const int ls0 = ps0 ^ (row0 & 7), ls1 = ps1 ^ (row1 & 7);

    bf16x8 k0r, k1r; short vreg[12];
    k0r = *(const bf16x8*)&Kb[base + (size_t)row0*DIM + ls0*8];
    k1r = *(const bf16x8*)&Kb[base + (size_t)row1*DIM + ls1*8];
#pragma unroll
    for (int j = 0; j < 12; ++j)
        vreg[j] = Vb[base + (size_t)lane*DIM + wid*12 + j];

    for (int t = 0; t < SEQ/64; ++t) {
        __syncthreads();
        *(bf16x8*)&K_lds[row0*64 + ps0*8] = k0r;
        *(bf16x8*)&K_lds[row1*64 + ps1*8] = k1r;
#pragma unroll
        for (int j = 0; j < 12; ++j)
            Vt_lds[(wid*12 + j)*68 + lane] = vreg[j];
        __syncthreads();

        if (t + 1 < SEQ/64) {
            int c0 = (t+1)*64;
            k0r = *(const bf16x8*)&Kb[base + (size_t)(c0 + row0)*DIM + ls0*8];
            k1r = *(const bf16x8*)&Kb[base + (size_t)(c0 + row1)*DIM + ls1*8];
#pragma unroll
            for (int j = 0; j < 12; ++j)
                vreg[j] = Vb[base + (size_t)(c0 + lane)*DIM + wid*12 + j];
        }

        f32x16 sa[2];
#pragma unroll
        for (int ct = 0; ct < 2; ++ct) {
            f32x16 a = z16;
#pragma unroll
            for (int s = 0; s < 3; ++s) {
                int row = ct*32 + r;
                bf16x8 kf = *(const bf16x8*)&K_lds[row*64 + ((s*2+hi) ^ (row&7))*8];
                a = __builtin_amdgcn_mfma_f32_32x32x16_bf16(kf, qf[s], a, 0, 0, 0);
            }
            sa[ct] = a;
        }

        float mx = -1e30f;
#pragma unroll
        for (int ct = 0; ct < 2; ++ct)
#pragma unroll
            for (int i = 0; i < 16; ++i) mx = fmaxf(mx, sa[ct][i]);
        mx = fmaxf(mx, __shfl_xor(mx, 32));
        mx *= C2;

        float mn = m_i;
        if (!__all(mx - m_i <= THR)) {
            mn = fmaxf(m_i, mx);
            float al = exp2f(m_i - mn);
            l_i *= al;
#pragma unroll
            for (int i = 0; i < 16; ++i) { acc0[i] *= al; acc1[i] *= al; }
            m_i = mn;
        }

        // p = exp2(s*C2 - mn); RNE-pack pairs; l from fp32 p (unbiased)
        float rs = 0.f;
        u32 w[2][8], sw[2][8];
#pragma unroll
        for (int ct = 0; ct < 2; ++ct)
#pragma unroll
            for (int k = 0; k < 8; ++k) {
                float p0 = exp2f(fmaf(sa[ct][2*k],   C2, -mn));
                float p1 = exp2f(fmaf(sa[ct][2*k+1], C2, -mn));
                w[ct][k] = cvtpk(p0, p1);
                rs += p0 + p1;
            }
        rs += __shfl_xor(rs, 32);
        l_i += rs;
#pragma unroll
        for (int ct = 0; ct < 2; ++ct)
#pragma unroll
            for (int k = 0; k < 8; ++k) sw[ct][k] = (u32)__shfl_xor((int)w[ct][k], 32);

#pragma unroll
        for (int ct = 0; ct < 2; ++ct)
#pragma unroll
            for (int hf = 0; hf < 2; ++hf) {
                u32 f0 = hi ? sw[ct][4*hf+2] : w[ct][4*hf+0];
                u32 f1 = hi ? sw[ct][4*hf+3] : w[ct][4*hf+1];
                u32 f2 = hi ? w[ct][4*hf+2]  : sw[ct][4*hf+0];
                u32 f3 = hi ? w[ct][4*hf+3]  : sw[ct][4*hf+1];
                int4 pw = make_int4((int)f0, (int)f1, (int)f2, (int)f3);
                bf16x8 pb = __builtin_bit_cast(bf16x8, pw);
#pragma unroll
                for (int dt = 0; dt < 2; ++dt) {
                    int off = (dt*32 + r)*68 + ct*32 + hf*16 + hi*8;
                    short4 v0 = *(const short4*)&Vt_lds[off];
                    short4 v1 = *(const short4*)&Vt_lds[off + 4];
                    bf16x8 av = {v0.x, v0.y, v0.z, v0.w, v1.x, v1.y, v1.z, v1.w};
                    if (dt == 0) acc0 = __builtin_amdgcn_mfma_f32_32x32x16_bf16(av, pb, acc0, 0, 0, 0);
                    else         acc1 = __builtin_amdgcn_mfma_f32_32x32x16_bf16(av, pb, acc1, 0, 0, 0);
                }
            }
    }

    float inv = 1.0f / l_i;
#pragma unroll
    for (int g = 0; g < 16; ++g) {
        int d = (g&3) + 8*(g>>2) + 4*hi;
        Ctx[base + (size_t)(q0 + r)*DIM + d] = f2bf(acc0[g] * inv);
    }
#pragma unroll
    for (int g = 0; g < 8; ++g) {
        int d = 32 + (g&3) + 8*(g>>2) + 4*hi;
        Ctx[base + (size_t)(q0 + r)*DIM + d] = f2bf(acc1[g] * inv);
    }
}

extern "C" void kernel_launch(void* const* d_in, const int* in_sizes, int n_in,
                              void* d_out, int out_size, void* d_ws, size_t ws_size,
                              hipStream_t stream)
{
    const float* x  = (const float*)d_in[0];
    const float* Wq = (const float*)d_in[1];
    const float* Wk = (const float*)d_in[2];
    const float* Wv = (const float*)d_in[3];
    const float* Wo = (const float*)d_in[4];
    float* out = (float*)d_out;

    const size_t XN = (size_t)NROWS * DIM;

    short* qb   = (short*)d_ws;
    short* kbuf = qb   + XN;
    short* vbuf = kbuf + XN;
    short* ctxb = vbuf + XN;                 // 25.2 MB total

    dim3 g1(DIM/96, NROWS/128, 3);           // 8 x 32 x 3 = 768 blocks
    gemm96<true, false><<<g1, 256, 0, stream>>>(x, Wq, Wk, Wv, qb, kbuf, vbuf);

    dim3 g2(SEQ/128, NH, NB);
    flash2<<<g2, 256, 0, stream>>>(qb, kbuf, vbuf, ctxb);

    dim3 g3(DIM/96, NROWS/128, 1);           // 256 blocks = 1.00/CU
    gemm96<false, true><<<g3, 256, 0, stream>>>(ctxb, Wo, Wo, Wo, out, out, out);
}